// Round 11
// baseline (82.423 us; speedup 1.0000x reference)
//
#include <hip/hip_runtime.h>

// SGC collapsed: out[g] = b2 + sum_{n in g}(dis_n*u1_n + b1.W2)
//                        + sum_{r->c} dis_c * u1_r          (hop2 fused w/ pool)
// v = W1@W2 (75), y0 = x.v, u0 = dis*y0, u1 = dis^2*(S1+u0), S1[c]=sum u0[r].
//
// LESSONS: R2 global-atomic wall; R6 grid.sync 37us; R7 threadfence storm;
// R8/R9 segment-search scatters slow; R4-R10 all ~75-97us regardless of
// structure while R7 proved dispatch boundaries are ~free => time hides in
// kernels under the 40us profiler cutoff; suspect = same-address LDS atomic
// funneling in the partition (2 passes x 6250 adds over 16 counters/block).
// FIX: per-wave cursors (no count pre-pass, ~4-way max serialization),
// per-(pblock,wave,range) segments streamed single-shot by scatter waves.

#define N_    50000
#define E_    800000
#define G_    512
#define F_    75
#define H_    128
#define RR    16         // col ranges
#define BINS  3125       // nodes per range (12 bits)
#define PBLK  256        // partition blocks
#define EPB   3125       // edges per partition block
#define SLOTW 40         // per (pblock,wave,range) slot cap (mean 12.2, +8 sigma)
#define CP    16         // scatter blocks per range
#define POOLB 256
#define NT    128        // nodes per k3 tile block

struct Pr {
    const float* x; const int* row; const int* col; const int* batch;
    const float* W1; const float* b1; const float* W2; const float* b2;
    float* u; float* u1; float2* kd; float* vv; float* cbw; int* bcnt;
    float* partial; unsigned* ebuf; float* out;
};

// ---- K1: partition edges with PER-WAVE cursors (single pass) + init ----
__global__ __launch_bounds__(1024)
void k1_part(Pr p) {
    const int t = threadIdx.x, b = blockIdx.x;
    __shared__ int wcur[256];            // [wave][range]
    if (t < 256) wcur[t] = 0;
    if (b == 0) {                        // one-block init duties
        if (t < G_) p.out[t] = p.b2[0];
        if (t == 600) {
            float s = 0.f;
            #pragma unroll 8
            for (int j = 0; j < H_; ++j) s += p.b1[j] * p.W2[j];
            p.cbw[0] = s;
        }
        if (t >= 640 && t < 640 + F_) {
            int i = t - 640;
            float s = 0.f;
            #pragma unroll 8
            for (int j = 0; j < H_; ++j) s += p.W1[i * H_ + j] * p.W2[j];
            p.vv[i] = s;
        }
    }
    __syncthreads();
    const int w = t >> 6;
    const int e0 = b * EPB;
    for (int e = e0 + t; e < e0 + EPB; e += 1024) {
        int cv = p.col[e];
        int r = cv / BINS;
        int k = atomicAdd(&wcur[w * 16 + r], 1);   // per-wave counter
        if (k < SLOTW)
            p.ebuf[(size_t)((b * 16 + w) * 16 + r) * SLOTW + k] =
                ((unsigned)p.row[e] << 12) | (unsigned)(cv - r * BINS);
    }
    __syncthreads();
    if (t < 256) {
        int c = wcur[t]; if (c > SLOTW) c = SLOTW;
        p.bcnt[b * 256 + t] = c;         // [b][w][r], fully rewritten each call
    }
}

// ---- K2/K4: scatter. Block (c,r): wave w streams pblock q=c*16+w ----
// HOP=0: deg += 1.  HOP=1: S1 += u0[packed>>12].  Single-shot: cnt <= 40 < 64.
template <int HOP>
__global__ __launch_bounds__(1024)
void k_scat(Pr p) {
    const int t = threadIdx.x;
    const int c = blockIdx.x, r = blockIdx.y;
    __shared__ float bins[BINS];
    for (int i = t; i < BINS; i += 1024) bins[i] = 0.f;
    __syncthreads();
    const int w = t >> 6, lane = t & 63;
    const int q = c * 16 + w;                       // this wave's pblock
    #pragma unroll
    for (int s = 0; s < 16; ++s) {                  // its 16 sub-wave segments
        int cnt = p.bcnt[q * 256 + s * 16 + r];     // broadcast load
        if (lane < cnt) {
            unsigned wd = p.ebuf[(size_t)((q * 16 + s) * 16 + r) * SLOTW + lane];
            float val = HOP ? p.u[wd >> 12] : 1.0f;
            atomicAdd(&bins[wd & 4095u], val);      // ds_add_f32
        }
    }
    __syncthreads();
    float* dst = p.partial + (size_t)c * N_ + r * BINS;
    for (int i = t; i < BINS; i += 1024) dst[i] = bins[i];
}

// ---- K3: y0 = x.v (float4 LDS tile), dis = rsqrt(1+deg), kd, u0 = dis*y0 ----
__global__ __launch_bounds__(1024)
void k3_fin0(Pr p) {
    const int t = threadIdx.x, b = blockIdx.x;
    __shared__ float xs[NT * F_];                   // 38.4KB
    __shared__ float sv[F_ + 1];
    if (t < F_) sv[t] = p.vv[t];
    const int n0 = b * NT;
    int rem = N_ - n0; if (rem > NT) rem = NT;
    const int nf4 = rem * F_ / 4;                   // exact (NT*75%4==0, tail too)
    const float4* xsrc = (const float4*)(p.x + (size_t)n0 * F_);
    for (int i = t; i < nf4; i += 1024) ((float4*)xs)[i] = xsrc[i];
    __syncthreads();
    const int ln = t >> 3, part = t & 7;            // 8 lanes per node
    if (ln < rem) {
        const float* xr = xs + ln * F_;
        float s = 0.f;
        for (int j = part; j < F_; j += 8) s += xr[j] * sv[j];
        s += __shfl_xor(s, 1);
        s += __shfl_xor(s, 2);
        s += __shfl_xor(s, 4);
        if (part == 0) {
            int i = n0 + ln;
            float dsum = 1.0f;                      // self-loop
            #pragma unroll
            for (int c = 0; c < CP; ++c) dsum += p.partial[(size_t)c * N_ + i];
            float d = rsqrtf(dsum);
            p.kd[i] = make_float2(d, __int_as_float(p.batch[i]));
            p.u[i] = d * s;                         // u0
        }
    }
}

// ---- K5: u1 = dis^2*(S1+u0) -> u1[]; node-term pool into out ----
__global__ __launch_bounds__(1024)
void k5_fin1(Pr p) {
    int i = blockIdx.x * 1024 + threadIdx.x;
    float val = 0.f; int g = -1;
    if (i < N_) {
        float s = 0.f;
        #pragma unroll
        for (int c = 0; c < CP; ++c) s += p.partial[(size_t)c * N_ + i];
        float2 k = p.kd[i];
        float nu = k.x * k.x * (s + p.u[i]);
        p.u1[i] = nu;
        val = k.x * nu + p.cbw[0];
        g = __float_as_int(k.y);
    }
    int g0 = __shfl(g, 0), g63 = __shfl(g, 63);
    if (g0 == g63 && g0 >= 0) {                     // sorted batch: 1 atomic/wave
        for (int o = 32; o; o >>= 1) val += __shfl_down(val, o);
        if ((threadIdx.x & 63) == 0) atomicAdd(&p.out[g0], val);
    } else if (g >= 0) {
        atomicAdd(&p.out[g], val);
    }
}

// ---- K6: edge-term pool (int4 loads, 512-bin LDS hist -> out atomics) ----
__global__ __launch_bounds__(1024)
void k6_pool(Pr p) {
    const int t = threadIdx.x, b = blockIdx.x;
    __shared__ float h[G_];
    for (int i = t; i < G_; i += 1024) h[i] = 0.f;
    __syncthreads();
    for (int q = b * 1024 + t; q < E_ / 4; q += POOLB * 1024) {
        int4 c4 = ((const int4*)p.col)[q];
        int4 r4 = ((const int4*)p.row)[q];
        float2 k0 = p.kd[c4.x], k1 = p.kd[c4.y], k2 = p.kd[c4.z], k3 = p.kd[c4.w];
        float a0 = p.u1[r4.x], a1 = p.u1[r4.y], a2 = p.u1[r4.z], a3 = p.u1[r4.w];
        atomicAdd(&h[__float_as_int(k0.y)], k0.x * a0);
        atomicAdd(&h[__float_as_int(k1.y)], k1.x * a1);
        atomicAdd(&h[__float_as_int(k2.y)], k2.x * a2);
        atomicAdd(&h[__float_as_int(k3.y)], k3.x * a3);
    }
    __syncthreads();
    for (int i = t; i < G_; i += 1024)
        if (h[i] != 0.f) atomicAdd(&p.out[i], h[i]);
}

// ================= fallback (plain atomic path, proven in round 2) ==========
__global__ void f_setup(const float* W1, const float* b1, const float* W2,
                        const float* b2, float* v, float* cb) {
    int t = threadIdx.x;
    if (t < F_) {
        float s = 0.f;
        for (int j = 0; j < H_; ++j) s += W1[t * H_ + j] * W2[j];
        v[t] = s;
    } else if (t == F_) {
        float s = 0.f;
        for (int j = 0; j < H_; ++j) s += b1[j] * W2[j];
        cb[0] = s; cb[1] = b2[0];
    }
}
__global__ void f_init(float* deg, float* s, int n) {
    int i = blockIdx.x * blockDim.x + threadIdx.x;
    if (i < n) { deg[i] = 1.0f; s[i] = 0.0f; }
}
__global__ void f_deg_acc(const int* __restrict__ col, float* deg, int e) {
    int i = blockIdx.x * blockDim.x + threadIdx.x;
    if (i < e) atomicAdd(&deg[col[i]], 1.0f);
}
__global__ void f_dis(float* deg, int n) {
    int i = blockIdx.x * blockDim.x + threadIdx.x;
    if (i < n) deg[i] = rsqrtf(deg[i]);
}
__global__ void f_u0(const float* __restrict__ x, const float* __restrict__ v,
                     const float* __restrict__ dis, float* u, int n) {
    __shared__ float sv[F_];
    if (threadIdx.x < F_) sv[threadIdx.x] = v[threadIdx.x];
    __syncthreads();
    int i = blockIdx.x * blockDim.x + threadIdx.x;
    if (i < n) {
        const float* xi = x + (size_t)i * F_;
        float s = 0.f;
        for (int j = 0; j < F_; ++j) s += xi[j] * sv[j];
        u[i] = dis[i] * s;
    }
}
__global__ void f_edge(const int* __restrict__ row, const int* __restrict__ col,
                       const float* __restrict__ u, float* s, int e) {
    int i = blockIdx.x * blockDim.x + threadIdx.x;
    if (i < e) atomicAdd(&s[col[i]], u[row[i]]);
}
__global__ void f_hop_finish(const float* __restrict__ dis, float* s, float* u, int n) {
    int i = blockIdx.x * blockDim.x + threadIdx.x;
    if (i < n) { float d = dis[i]; u[i] = d * d * (s[i] + u[i]); s[i] = 0.0f; }
}
__global__ void f_out_init(const float* __restrict__ cb, float* out, int g) {
    int i = blockIdx.x * blockDim.x + threadIdx.x;
    if (i < g) out[i] = cb[1];
}
__global__ void f_pool(const int* __restrict__ batch, const float* __restrict__ dis,
                       const float* __restrict__ s, const float* __restrict__ u,
                       const float* __restrict__ cb, float* out, int n) {
    int i = blockIdx.x * blockDim.x + threadIdx.x;
    if (i < n) atomicAdd(&out[batch[i]], dis[i] * (s[i] + u[i]) + cb[0]);
}
// ============================================================================

extern "C" void kernel_launch(void* const* d_in, const int* in_sizes, int n_in,
                              void* d_out, int out_size, void* d_ws, size_t ws_size,
                              hipStream_t stream) {
    const float* x   = (const float*)d_in[0];
    const int*   ei  = (const int*)d_in[1];   // [2,E] int32 (harness converts ints)
    const int*   bat = (const int*)d_in[2];   // [N] int32, sorted
    const float* W1  = (const float*)d_in[3];
    const float* b1  = (const float*)d_in[4];
    const float* W2  = (const float*)d_in[5];
    const float* b2  = (const float*)d_in[6];
    float* out = (float*)d_out;

    float* ws = (float*)d_ws;
    Pr p;
    p.x = x; p.row = ei; p.col = ei + E_; p.batch = bat;
    p.W1 = W1; p.b1 = b1; p.W2 = W2; p.b2 = b2;
    p.u       = ws;                                   // N
    p.u1      = ws + N_;                              // N
    p.kd      = (float2*)(ws + 2 * N_);               // 2N (even offset, 8B ok)
    p.vv      = ws + 4 * N_;                          // 128
    p.cbw     = ws + 4 * N_ + 128;                    // 8
    p.bcnt    = (int*)(ws + 4 * N_ + 136);            // PBLK*256
    p.partial = ws + 4 * N_ + 136 + PBLK * 256;       // CP*N
    p.ebuf    = (unsigned*)(p.partial + (size_t)CP * N_);  // PBLK*16*16*SLOTW
    p.out     = out;

    const size_t need = ((size_t)4 * N_ + 136 + PBLK * 256 + (size_t)CP * N_
                         + (size_t)PBLK * 256 * SLOTW) * sizeof(float);

    if (ws_size >= need) {
        k1_part<<<PBLK, 1024, 0, stream>>>(p);
        k_scat<0><<<dim3(CP, RR), 1024, 0, stream>>>(p);
        k3_fin0<<<(N_ + NT - 1) / NT, 1024, 0, stream>>>(p);
        k_scat<1><<<dim3(CP, RR), 1024, 0, stream>>>(p);
        k5_fin1<<<(N_ + 1023) / 1024, 1024, 0, stream>>>(p);
        k6_pool<<<POOLB, 1024, 0, stream>>>(p);
    } else {
        // plain atomic fallback: v 128 | cb 8 | dis N | u N | s N
        float* v  = ws;
        float* cb = ws + 128;
        float* dis = ws + 136;
        float* u  = dis + N_;
        float* s  = u + N_;
        const int B = 256;
        const int gN = (N_ + B - 1) / B;
        const int gE = (E_ + B - 1) / B;
        f_setup<<<1, 128, 0, stream>>>(W1, b1, W2, b2, v, cb);
        f_init<<<gN, B, 0, stream>>>(dis, s, N_);
        f_deg_acc<<<gE, B, 0, stream>>>(ei + E_, dis, E_);
        f_dis<<<gN, B, 0, stream>>>(dis, N_);
        f_u0<<<gN, B, 0, stream>>>(x, v, dis, u, N_);
        f_edge<<<gE, B, 0, stream>>>(ei, ei + E_, u, s, E_);
        f_hop_finish<<<gN, B, 0, stream>>>(dis, s, u, N_);
        f_out_init<<<1, G_, 0, stream>>>(cb, out, G_);
        f_edge<<<gE, B, 0, stream>>>(ei, ei + E_, u, s, E_);
        f_pool<<<gN, B, 0, stream>>>(bat, dis, s, u, cb, out, N_);
    }
}